// Round 1
// 471.869 us; speedup vs baseline: 1.0096x; 1.0096x over previous
//
#include <hip/hip_runtime.h>
#include <hip/hip_fp16.h>

typedef _Float16 f16;
typedef _Float16 f16x2 __attribute__((ext_vector_type(2)));
typedef _Float16 f16x8 __attribute__((ext_vector_type(8)));
typedef float    f32x4 __attribute__((ext_vector_type(4)));

#define NB   8192
#define TOUT 10
#define LMAX 12
#define EMB  300

__device__ __forceinline__ float sigm_(float x) {
    return __builtin_amdgcn_rcpf(1.0f + __builtin_amdgcn_exp2f(x * -1.44269504f));
}
__device__ __forceinline__ float tanh_(float x) {
    return 1.0f - 2.0f * __builtin_amdgcn_rcpf(1.0f + __builtin_amdgcn_exp2f(x * 2.88539008f));
}
__device__ __forceinline__ f16x2 pk_f16(float a, float b) {
    return __builtin_bit_cast(f16x2, __builtin_amdgcn_cvt_pkrtz(a, b));
}

// ---------------------------------------------------------------------------
// K0a: pack LSTM weights into MFMA B-fragment tiles, f16, gate-permuted cols.
// Dest per dir: [kc 0..15][ntile 0..63][512 f16]; within tile element (k,n):
// offset = ((k%32)/8*16 + n%16)*8 + k%8 (lane l reads l*8..l*8+7).
// NEW column permutation (16-wave / 64-col-per-wave gate split):
//   n -> w2 = n/64 (wave), gate = (n>>4)&3, unit u = w2*16 + (n&15)
// so each wave's 4 n-tiles are the 4 gates of units [w2*16, w2*16+16).
// ---------------------------------------------------------------------------
__global__ __launch_bounds__(256) void pack_w2(
    const float* __restrict__ wih_f, const float* __restrict__ whh_f,
    const float* __restrict__ wih_b, const float* __restrict__ whh_b,
    f16* __restrict__ Wp) {
    int idx = blockIdx.x * 256 + threadIdx.x;   // 0 .. 2*524288-1
    int d   = idx >> 19;
    int r   = idx & 524287;
    int tile = r >> 9;
    int e    = r & 511;
    int kc = tile >> 6, nt = tile & 63;
    int khi = e >> 7, rem = e & 127, nl = rem >> 3, klo = rem & 7;
    int n = nt * 16 + nl;
    int k = kc * 32 + khi * 8 + klo;
    int gate = (n >> 4) & 3;
    int u = ((n >> 6) << 4) | (n & 15);
    int srow = gate * 256 + u;
    const float* wih = d ? wih_b : wih_f;
    const float* whh = d ? whh_b : whh_f;
    float v = (k < 256) ? wih[srow * 256 + k] : whh[srow * 256 + (k - 256)];
    Wp[idx] = (f16)v;
}

__global__ __launch_bounds__(256) void pack_bias(
    const float* __restrict__ bih_f, const float* __restrict__ bhh_f,
    const float* __restrict__ bih_b, const float* __restrict__ bhh_b,
    float* __restrict__ bp) {
    int idx = blockIdx.x * 256 + threadIdx.x;   // 2048
    int d = idx >> 10, n = idx & 1023;
    int gate = (n >> 4) & 3;
    int u = ((n >> 6) << 4) | (n & 15);
    int srow = gate * 256 + u;
    bp[idx] = d ? (bih_b[srow] + bhh_b[srow]) : (bih_f[srow] + bhh_f[srow]);
}

// K0b: pack out_w (512x512) into B-fragment tiles: [kc 0..15][ntile 0..31][512]
__global__ __launch_bounds__(256) void pack_w3(
    const float* __restrict__ out_w, f16* __restrict__ W3p) {
    int idx = blockIdx.x * 256 + threadIdx.x;   // 262144
    int tile = idx >> 9, e = idx & 511;
    int kc = tile >> 5, nt = tile & 31;
    int khi = e >> 7, rem = e & 127, nl = rem >> 3, klo = rem & 7;
    int n = nt * 16 + nl, k = kc * 32 + khi * 8 + klo;
    W3p[idx] = (f16)out_w[n * 512 + k];
}

// K0c: P[36][256] = emb_table @ enc_w^T + enc_b (fp32)
__global__ __launch_bounds__(256) void enc_proj(
    const float* __restrict__ tab, const float* __restrict__ ew,
    const float* __restrict__ eb, float* __restrict__ P) {
    int v = blockIdx.x, j = threadIdx.x;
    const float* a = tab + v * EMB;
    const float* w = ew + j * EMB;
    float s = 0.0f;
    for (int k = 0; k < EMB; ++k) s += a[k] * w[k];
    P[v * 256 + j] = s + eb[j];
}

// ---------------------------------------------------------------------------
// K1: build seq in MFMA A-fragment tile layout, f16.
// seqp: [t 0..9][mtile 0..511][kc 0..7][512 f16]; element (row,k):
// offset = ((k%32)/8*16 + row%16)*8 + k%8
// ---------------------------------------------------------------------------
__global__ __launch_bounds__(256) void build_seq(
    const int* __restrict__ words, const int* __restrict__ lengths,
    const float* __restrict__ P, f16* __restrict__ seqp) {
    int gi = blockIdx.x * 256 + threadIdx.x;    // 2,621,440 total
    int bl  = gi & 15;
    int khi = (gi >> 4) & 3;
    int kc  = (gi >> 6) & 7;
    int mt  = (gi >> 9) & 511;
    int t   = gi >> 18;
    int b = mt * 16 + bl;
    int L = lengths[b];
    float pos = ((float)t * (float)(L - 1)) / 9.0f;
    int i0 = (int)pos;
    float f = pos - (float)i0;
    int i1 = min(i0 + 1, L - 1);
    int c0 = words[b * LMAX + i0];
    int c1 = words[b * LMAX + i1];
    const float* p0 = P + c0 * 256 + kc * 32 + khi * 8;
    const float* p1 = P + c1 * 256 + kc * 32 + khi * 8;
    f16x8 r;
#pragma unroll
    for (int j = 0; j < 8; ++j) {
        float v = p0[j] * (1.0f - f) + p1[j] * f;
        v = fmaxf(v, 0.0f);
        r[j] = (f16)v;
    }
    *((f16x8*)seqp + gi) = r;
}

// ---------------------------------------------------------------------------
// K2: fused BiLSTM. 256 blocks (128 fwd + 128 bwd) x 1024 thr (16 waves).
// 1 block/CU -> 16 waves/CU = 4 waves/SIMD (was 2: grid-limited occupancy
// was the round-0 bottleneck, MfmaUtil 37%). Block owns 64 batch rows and
// ALL 1024 gate-cols (recurrence forces full-unit ownership); wave tile is
// 64 rows x 64 gate-cols = 4 gates x 16 units, so per-block weight traffic
// stays 1 MB/step (16 waves read disjoint 64 KB slices) -- the L2 weight
// stream does NOT double the way a 512-block split would.
// Double-buffered h (2x32KB LDS), ONE barrier per step. h written directly
// to LDS (recurrence) + global hcat (scalar f16 stores, 1 unit/lane/cell).
// ---------------------------------------------------------------------------
__global__ __launch_bounds__(1024) void lstm_fused(
    const f16* __restrict__ seqp, const f16* __restrict__ Wp,
    const float* __restrict__ bp, f16* __restrict__ hcat) {
    const int dir  = blockIdx.x >> 7;
    const int r0t  = (blockIdx.x & 127) << 2;   // row-tile base, 4 tiles of 16
    const int wave = threadIdx.x >> 6;          // 0..15
    const int lane = threadIdx.x & 63;
    const int l16  = lane & 15;
    const int quad = lane >> 4;

    __shared__ __align__(16) f16 hbuf[2][4 * 8 * 512];   // 2 x 32 KB

    // zero h0 buffer
    {
        f16x8 z = {(f16)0, (f16)0, (f16)0, (f16)0, (f16)0, (f16)0, (f16)0, (f16)0};
        for (int i = threadIdx.x; i < 2048; i += 1024) ((f16x8*)hbuf[0])[i] = z;
    }

    // per-lane gate biases: wave owns cols [wave*64, wave*64+64); nt = gate
    const float* bpd = bp + dir * 1024 + wave * 64;
    float bias_l[4];
#pragma unroll
    for (int nt = 0; nt < 4; ++nt) bias_l[nt] = bpd[nt * 16 + l16];

    // weight base: fold dir, wave col-group, and lane into the pointer
    const f16* Wd = Wp + dir * 524288 + (wave * 4) * 512 + lane * 8;

    // this lane's h-unit: u = wave*16 + l16  (one unit per lane)
    // hcat/LDS A-fragment tile: kcl = u>>5 = wave>>1; kk = u&31;
    // offset(row) = ((kk>>3)*16 + row)*8 + (kk&7)
    const int slot = wave >> 1;                  // k-chunk 0..7 within dir
    const int ofs0 = (((wave & 1) * 2 + (l16 >> 3)) * 16 + quad * 4) * 8 + (l16 & 7);
    const int tile_lo = (r0t * 16 + dir * 8 + slot) * 512;

    float cst[4][4];
#pragma unroll
    for (int m = 0; m < 4; ++m)
#pragma unroll
        for (int q = 0; q < 4; ++q) cst[m][q] = 0.0f;

    __syncthreads();

    int cur = 0;
#pragma unroll 1
    for (int step = 0; step < TOUT; ++step) {
        const int t = dir ? (9 - step) : step;
        const f16* hb_r = hbuf[cur] + lane * 8;
        f16*       hb_w = hbuf[cur ^ 1];

        f32x4 acc[4][4];
#pragma unroll
        for (int m = 0; m < 4; ++m)
#pragma unroll
            for (int nt = 0; nt < 4; ++nt)
#pragma unroll
                for (int q = 0; q < 4; ++q) acc[m][nt][q] = bias_l[nt];

        const f16* seqt = seqp + (size_t)(t * 512 + r0t) * 4096 + lane * 8;

        // K chunks 0..7: A from seq (global, fragment-packed)
#pragma unroll 1
        for (int kc = 0; kc < 8; ++kc) {
            f16x8 bfrag[4];
#pragma unroll
            for (int nt = 0; nt < 4; ++nt)
                bfrag[nt] = *(const f16x8*)(Wd + (kc * 64 + nt) * 512);
            f16x8 afrag[4];
#pragma unroll
            for (int m = 0; m < 4; ++m)
                afrag[m] = *(const f16x8*)(seqt + (m * 8 + kc) * 512);
#pragma unroll
            for (int m = 0; m < 4; ++m)
#pragma unroll
                for (int nt = 0; nt < 4; ++nt)
                    acc[m][nt] = __builtin_amdgcn_mfma_f32_16x16x32_f16(
                        afrag[m], bfrag[nt], acc[m][nt], 0, 0, 0);
        }
        // K chunks 8..15: A = h (LDS, fragment-packed)
#pragma unroll 1
        for (int kcl = 0; kcl < 8; ++kcl) {
            int kc = kcl + 8;
            f16x8 bfrag[4];
#pragma unroll
            for (int nt = 0; nt < 4; ++nt)
                bfrag[nt] = *(const f16x8*)(Wd + (kc * 64 + nt) * 512);
            f16x8 afrag[4];
#pragma unroll
            for (int m = 0; m < 4; ++m)
                afrag[m] = *(const f16x8*)(hb_r + (m * 8 + kcl) * 512);
#pragma unroll
            for (int m = 0; m < 4; ++m)
#pragma unroll
                for (int nt = 0; nt < 4; ++nt)
                    acc[m][nt] = __builtin_amdgcn_mfma_f32_16x16x32_f16(
                        afrag[m], bfrag[nt], acc[m][nt], 0, 0, 0);
        }

        // lane-local gate combine; h -> LDS (for recurrence) + global hcat.
        // acc[m][nt][q]: row = m*16 + quad*4 + q, gate = nt, unit = wave*16+l16
        f16* hct = hcat + ((size_t)t * 4194304 + tile_lo);
#pragma unroll
        for (int m = 0; m < 4; ++m) {
#pragma unroll
            for (int q = 0; q < 4; ++q) {
                float iv = acc[m][0][q];
                float fv = acc[m][1][q];
                float gv = acc[m][2][q];
                float ov = acc[m][3][q];
                float c = sigm_(fv) * cst[m][q] + sigm_(iv) * tanh_(gv);
                cst[m][q] = c;
                f16 hv = (f16)(sigm_(ov) * tanh_(c));
                int wt = ofs0 + q * 8;
                hb_w[(m * 8 + slot) * 512 + wt] = hv;
                hct[m * 8192 + wt] = hv;
            }
        }

        __syncthreads();   // single barrier per step
        cur ^= 1;
    }
}

// ---------------------------------------------------------------------------
// K3: out = h_cat(81920x512 f16, frag layout) @ W3p + out_b -> fp32 (B,10,512)
// 1280 blocks x 512 thr; block tile 64 rows x 512 cols; wave: 64x64.
// ---------------------------------------------------------------------------
__global__ __launch_bounds__(512) void out_gemm(
    const f16* __restrict__ hcat, const f16* __restrict__ W3p,
    const float* __restrict__ out_b, float* __restrict__ out) {
    const int mt0  = blockIdx.x << 2;
    const int wave = threadIdx.x >> 6;
    const int lane = threadIdx.x & 63;
    const int l16  = lane & 15;
    const int quad = lane >> 4;
    const int n0   = wave * 64;

    float bias_l[4];
#pragma unroll
    for (int nt = 0; nt < 4; ++nt) bias_l[nt] = out_b[n0 + nt * 16 + l16];

    f32x4 acc[4][4];
#pragma unroll
    for (int m = 0; m < 4; ++m)
#pragma unroll
        for (int nt = 0; nt < 4; ++nt)
#pragma unroll
            for (int q = 0; q < 4; ++q) acc[m][nt][q] = bias_l[nt];

#pragma unroll 2
    for (int kc = 0; kc < 16; ++kc) {
        f16x8 a[4], b[4];
#pragma unroll
        for (int m = 0; m < 4; ++m)
            a[m] = *(const f16x8*)(hcat + ((size_t)((mt0 + m) * 16 + kc) * 512 + lane * 8));
#pragma unroll
        for (int nt = 0; nt < 4; ++nt)
            b[nt] = *(const f16x8*)(W3p + ((kc * 32 + wave * 4 + nt) * 512 + lane * 8));
#pragma unroll
        for (int m = 0; m < 4; ++m)
#pragma unroll
            for (int nt = 0; nt < 4; ++nt)
                acc[m][nt] = __builtin_amdgcn_mfma_f32_16x16x32_f16(a[m], b[nt], acc[m][nt], 0, 0, 0);
    }

#pragma unroll
    for (int m = 0; m < 4; ++m) {
#pragma unroll
        for (int nt = 0; nt < 4; ++nt) {
#pragma unroll
            for (int q = 0; q < 4; ++q) {
                int R = mt0 * 16 + m * 16 + quad * 4 + q;
                int t = R >> 13;
                int b = R & 8191;
                out[(size_t)(b * 10 + t) * 512 + n0 + nt * 16 + l16] = acc[m][nt][q];
            }
        }
    }
}

// ---------------------------------------------------------------------------
extern "C" void kernel_launch(void* const* d_in, const int* in_sizes, int n_in,
                              void* d_out, int out_size, void* d_ws, size_t ws_size,
                              hipStream_t stream) {
    const int*   words   = (const int*)d_in[0];
    const int*   lengths = (const int*)d_in[1];
    const float* tab     = (const float*)d_in[2];
    const float* enc_w   = (const float*)d_in[3];
    const float* enc_b   = (const float*)d_in[4];
    const float* wih_f   = (const float*)d_in[5];
    const float* whh_f   = (const float*)d_in[6];
    const float* bih_f   = (const float*)d_in[7];
    const float* bhh_f   = (const float*)d_in[8];
    const float* wih_b   = (const float*)d_in[9];
    const float* whh_b   = (const float*)d_in[10];
    const float* bih_b   = (const float*)d_in[11];
    const float* bhh_b   = (const float*)d_in[12];
    const float* out_w   = (const float*)d_in[13];
    const float* out_b   = (const float*)d_in[14];
    float* out = (float*)d_out;

    char* ws = (char*)d_ws;
    f16*   Wp   = (f16*)(ws + 0);           //  2 MB
    f16*   W3p  = (f16*)(ws + 2097152);     //  0.5 MB
    float* bp   = (float*)(ws + 2621440);   //  8 KB
    float* P    = (float*)(ws + 2629632);   //  36 KB
    f16*   seqp = (f16*)(ws + 2666496);     //  40 MB
    f16*   hcat = (f16*)(ws + 44609536);    //  80 MB  (total ~122.6 MB)

    pack_w2<<<4096, 256, 0, stream>>>(wih_f, whh_f, wih_b, whh_b, Wp);
    pack_bias<<<8, 256, 0, stream>>>(bih_f, bhh_f, bih_b, bhh_b, bp);
    pack_w3<<<1024, 256, 0, stream>>>(out_w, W3p);
    enc_proj<<<36, 256, 0, stream>>>(tab, enc_w, enc_b, P);
    build_seq<<<10240, 256, 0, stream>>>(words, lengths, P, seqp);
    lstm_fused<<<256, 1024, 0, stream>>>(seqp, Wp, bp, hcat);
    out_gemm<<<1280, 512, 0, stream>>>(hcat, W3p, out_b, out);
}

// Round 2
// 456.418 us; speedup vs baseline: 1.0438x; 1.0339x over previous
//
#include <hip/hip_runtime.h>
#include <hip/hip_fp16.h>

typedef _Float16 f16;
typedef _Float16 f16x2 __attribute__((ext_vector_type(2)));
typedef _Float16 f16x8 __attribute__((ext_vector_type(8)));
typedef float    f32x4 __attribute__((ext_vector_type(4)));

#define NB   8192
#define TOUT 10
#define LMAX 12
#define EMB  300

__device__ __forceinline__ float sigm_(float x) {
    return __builtin_amdgcn_rcpf(1.0f + __builtin_amdgcn_exp2f(x * -1.44269504f));
}
__device__ __forceinline__ float tanh_(float x) {
    return 1.0f - 2.0f * __builtin_amdgcn_rcpf(1.0f + __builtin_amdgcn_exp2f(x * 2.88539008f));
}
__device__ __forceinline__ f16x2 pk_f16(float a, float b) {
    return __builtin_bit_cast(f16x2, __builtin_amdgcn_cvt_pkrtz(a, b));
}

// async global->LDS, 16B per lane. LDS dest is wave-uniform base + lane*16.
__device__ __forceinline__ void gl_lds16(const f16* g, f16* l) {
    __builtin_amdgcn_global_load_lds(
        (const __attribute__((address_space(1))) void*)g,
        (__attribute__((address_space(3))) void*)l, 16, 0, 0);
}

// ---------------------------------------------------------------------------
// K0a: pack LSTM weights into MFMA B-fragment tiles, f16, gate-permuted cols.
// Dest per dir: [kc 0..15][ntile 0..63][512 f16]; within tile element (k,n):
// offset = ((k%32)/8*16 + n%16)*8 + k%8 (lane l reads l*8..l*8+7).
// Column permutation (16-wave / 64-col-per-wave gate split):
//   n -> w2 = n/64 (wave), gate = (n>>4)&3, unit u = w2*16 + (n&15)
// ---------------------------------------------------------------------------
__global__ __launch_bounds__(256) void pack_w2(
    const float* __restrict__ wih_f, const float* __restrict__ whh_f,
    const float* __restrict__ wih_b, const float* __restrict__ whh_b,
    f16* __restrict__ Wp) {
    int idx = blockIdx.x * 256 + threadIdx.x;   // 0 .. 2*524288-1
    int d   = idx >> 19;
    int r   = idx & 524287;
    int tile = r >> 9;
    int e    = r & 511;
    int kc = tile >> 6, nt = tile & 63;
    int khi = e >> 7, rem = e & 127, nl = rem >> 3, klo = rem & 7;
    int n = nt * 16 + nl;
    int k = kc * 32 + khi * 8 + klo;
    int gate = (n >> 4) & 3;
    int u = ((n >> 6) << 4) | (n & 15);
    int srow = gate * 256 + u;
    const float* wih = d ? wih_b : wih_f;
    const float* whh = d ? whh_b : whh_f;
    float v = (k < 256) ? wih[srow * 256 + k] : whh[srow * 256 + (k - 256)];
    Wp[idx] = (f16)v;
}

__global__ __launch_bounds__(256) void pack_bias(
    const float* __restrict__ bih_f, const float* __restrict__ bhh_f,
    const float* __restrict__ bih_b, const float* __restrict__ bhh_b,
    float* __restrict__ bp) {
    int idx = blockIdx.x * 256 + threadIdx.x;   // 2048
    int d = idx >> 10, n = idx & 1023;
    int gate = (n >> 4) & 3;
    int u = ((n >> 6) << 4) | (n & 15);
    int srow = gate * 256 + u;
    bp[idx] = d ? (bih_b[srow] + bhh_b[srow]) : (bih_f[srow] + bhh_f[srow]);
}

// K0b: pack out_w (512x512) into B-fragment tiles: [kc 0..15][ntile 0..31][512]
__global__ __launch_bounds__(256) void pack_w3(
    const float* __restrict__ out_w, f16* __restrict__ W3p) {
    int idx = blockIdx.x * 256 + threadIdx.x;   // 262144
    int tile = idx >> 9, e = idx & 511;
    int kc = tile >> 5, nt = tile & 31;
    int khi = e >> 7, rem = e & 127, nl = rem >> 3, klo = rem & 7;
    int n = nt * 16 + nl, k = kc * 32 + khi * 8 + klo;
    W3p[idx] = (f16)out_w[n * 512 + k];
}

// K0c: P[36][256] = emb_table @ enc_w^T + enc_b (fp32)
__global__ __launch_bounds__(256) void enc_proj(
    const float* __restrict__ tab, const float* __restrict__ ew,
    const float* __restrict__ eb, float* __restrict__ P) {
    int v = blockIdx.x, j = threadIdx.x;
    const float* a = tab + v * EMB;
    const float* w = ew + j * EMB;
    float s = 0.0f;
    for (int k = 0; k < EMB; ++k) s += a[k] * w[k];
    P[v * 256 + j] = s + eb[j];
}

// ---------------------------------------------------------------------------
// K1: build seq in MFMA A-fragment tile layout, f16.
// seqp: [t 0..9][mtile 0..511][kc 0..7][512 f16]; element (row,k):
// offset = ((k%32)/8*16 + row%16)*8 + k%8
// ---------------------------------------------------------------------------
__global__ __launch_bounds__(256) void build_seq(
    const int* __restrict__ words, const int* __restrict__ lengths,
    const float* __restrict__ P, f16* __restrict__ seqp) {
    int gi = blockIdx.x * 256 + threadIdx.x;    // 2,621,440 total
    int bl  = gi & 15;
    int khi = (gi >> 4) & 3;
    int kc  = (gi >> 6) & 7;
    int mt  = (gi >> 9) & 511;
    int t   = gi >> 18;
    int b = mt * 16 + bl;
    int L = lengths[b];
    float pos = ((float)t * (float)(L - 1)) / 9.0f;
    int i0 = (int)pos;
    float f = pos - (float)i0;
    int i1 = min(i0 + 1, L - 1);
    int c0 = words[b * LMAX + i0];
    int c1 = words[b * LMAX + i1];
    const float* p0 = P + c0 * 256 + kc * 32 + khi * 8;
    const float* p1 = P + c1 * 256 + kc * 32 + khi * 8;
    f16x8 r;
#pragma unroll
    for (int j = 0; j < 8; ++j) {
        float v = p0[j] * (1.0f - f) + p1[j] * f;
        v = fmaxf(v, 0.0f);
        r[j] = (f16)v;
    }
    *((f16x8*)seqp + gi) = r;
}

// ---------------------------------------------------------------------------
// K2: fused BiLSTM. 256 blocks (128 fwd + 128 bwd) x 1024 thr (16 waves),
// 1 block/CU, 4 waves/SIMD (VGPR 64 arch + 64 AGPR acc = exactly the 128 cap
// -- any added register pressure drops occupancy, so all round-2 changes are
// register-neutral).
// Round-2: seq tile (32 KB, shared by all 16 waves) is staged to LDS with
// global_load_lds and PREFETCHED one step ahead -- issue at step start, the
// step-ending barrier drains it, so HBM/L2 latency hides under ~19 us of
// compute. Phase-A A-fragments become ds_read_b128. This removes the
// post-barrier L2-latency convoy and ~0.5 MB/step of redundant per-CU L2
// traffic (weights remain the only global stream: 1 MB/block/step).
// setprio(1) wraps each MFMA cluster (waves now have role diversity:
// stage-issuing vs MFMA-issuing).
// ---------------------------------------------------------------------------
__global__ __launch_bounds__(1024) void lstm_fused(
    const f16* __restrict__ seqp, const f16* __restrict__ Wp,
    const float* __restrict__ bp, f16* __restrict__ hcat) {
    const int dir  = blockIdx.x >> 7;
    const int r0t  = (blockIdx.x & 127) << 2;   // row-tile base, 4 tiles of 16
    const int wave = threadIdx.x >> 6;          // 0..15
    const int lane = threadIdx.x & 63;
    const int l16  = lane & 15;
    const int quad = lane >> 4;

    __shared__ __align__(16) f16 hbuf[2][16384];   // 2 x 32 KB  h state
    __shared__ __align__(16) f16 sbuf[2][16384];   // 2 x 32 KB  seq tiles

    // zero h0 buffer
    {
        f16x8 z = {(f16)0, (f16)0, (f16)0, (f16)0, (f16)0, (f16)0, (f16)0, (f16)0};
        for (int i = threadIdx.x; i < 2048; i += 1024) ((f16x8*)hbuf[0])[i] = z;
    }

    // stage seq tile for t0 into sbuf[0] (2 rounds x 16 KB)
    {
        const int t0 = dir ? 9 : 0;
        const f16* s0 = seqp + (size_t)(t0 * 512 + r0t) * 4096;
        gl_lds16(s0 + threadIdx.x * 8,        &sbuf[0][wave * 512]);
        gl_lds16(s0 + 8192 + threadIdx.x * 8, &sbuf[0][8192 + wave * 512]);
    }

    // per-lane gate biases: wave owns cols [wave*64, wave*64+64); nt = gate
    const float* bpd = bp + dir * 1024 + wave * 64;
    float bias_l[4];
#pragma unroll
    for (int nt = 0; nt < 4; ++nt) bias_l[nt] = bpd[nt * 16 + l16];

    // weights: uniform base per wave + per-lane offset (saddr-friendly)
    const f16* Wu = Wp + dir * 524288 + wave * 2048;   // uniform
    const int  wo = lane * 8;                           // divergent, constant

    // this lane's h-unit: u = wave*16 + l16  (one unit per lane)
    const int slot = wave >> 1;                  // k-chunk 0..7 within dir
    const int ofs0 = (((wave & 1) * 2 + (l16 >> 3)) * 16 + quad * 4) * 8 + (l16 & 7);
    const int tile_lo = (r0t * 16 + dir * 8 + slot) * 512;

    float cst[4][4];
#pragma unroll
    for (int m = 0; m < 4; ++m)
#pragma unroll
        for (int q = 0; q < 4; ++q) cst[m][q] = 0.0f;

    __syncthreads();   // covers h0 zero + t0 seq stage (barrier drains vmcnt)

    int cur = 0;
#pragma unroll 1
    for (int step = 0; step < TOUT; ++step) {
        const int t = dir ? (9 - step) : step;

        // prefetch seq[t+-1] into sbuf[cur^1]; drained by this step's barrier
        if (step != 9) {
            const int tn = dir ? (t - 1) : (t + 1);
            const f16* ns = seqp + (size_t)(tn * 512 + r0t) * 4096;
            gl_lds16(ns + threadIdx.x * 8,        &sbuf[cur ^ 1][wave * 512]);
            gl_lds16(ns + 8192 + threadIdx.x * 8, &sbuf[cur ^ 1][8192 + wave * 512]);
        }

        const f16* sb   = &sbuf[cur][lane * 8];
        const f16* hb_r = &hbuf[cur][lane * 8];
        f16*       hb_w = hbuf[cur ^ 1];

        f32x4 acc[4][4];
#pragma unroll
        for (int m = 0; m < 4; ++m)
#pragma unroll
            for (int nt = 0; nt < 4; ++nt)
#pragma unroll
                for (int q = 0; q < 4; ++q) acc[m][nt][q] = bias_l[nt];

        // K chunks 0..7: A from seq (LDS, fragment-packed)
#pragma unroll 1
        for (int kc = 0; kc < 8; ++kc) {
            const f16* wk = Wu + kc * 32768;      // uniform per iter
            f16x8 bfrag[4];
#pragma unroll
            for (int nt = 0; nt < 4; ++nt)
                bfrag[nt] = *(const f16x8*)(wk + nt * 512 + wo);
            f16x8 afrag[4];
#pragma unroll
            for (int m = 0; m < 4; ++m)
                afrag[m] = *(const f16x8*)(sb + (m * 8 + kc) * 512);
            __builtin_amdgcn_s_setprio(1);
#pragma unroll
            for (int m = 0; m < 4; ++m)
#pragma unroll
                for (int nt = 0; nt < 4; ++nt)
                    acc[m][nt] = __builtin_amdgcn_mfma_f32_16x16x32_f16(
                        afrag[m], bfrag[nt], acc[m][nt], 0, 0, 0);
            __builtin_amdgcn_s_setprio(0);
        }
        // K chunks 8..15: A = h (LDS, fragment-packed)
#pragma unroll 1
        for (int kcl = 0; kcl < 8; ++kcl) {
            const f16* wk = Wu + (kcl + 8) * 32768;
            f16x8 bfrag[4];
#pragma unroll
            for (int nt = 0; nt < 4; ++nt)
                bfrag[nt] = *(const f16x8*)(wk + nt * 512 + wo);
            f16x8 afrag[4];
#pragma unroll
            for (int m = 0; m < 4; ++m)
                afrag[m] = *(const f16x8*)(hb_r + (m * 8 + kcl) * 512);
            __builtin_amdgcn_s_setprio(1);
#pragma unroll
            for (int m = 0; m < 4; ++m)
#pragma unroll
                for (int nt = 0; nt < 4; ++nt)
                    acc[m][nt] = __builtin_amdgcn_mfma_f32_16x16x32_f16(
                        afrag[m], bfrag[nt], acc[m][nt], 0, 0, 0);
            __builtin_amdgcn_s_setprio(0);
        }

        // lane-local gate combine; h -> LDS (for recurrence) + global hcat.
        // acc[m][nt][q]: row = m*16 + quad*4 + q, gate = nt, unit = wave*16+l16
        f16* hct = hcat + ((size_t)t * 4194304 + tile_lo);
#pragma unroll
        for (int m = 0; m < 4; ++m) {
#pragma unroll
            for (int q = 0; q < 4; ++q) {
                float iv = acc[m][0][q];
                float fv = acc[m][1][q];
                float gv = acc[m][2][q];
                float ov = acc[m][3][q];
                float c = sigm_(fv) * cst[m][q] + sigm_(iv) * tanh_(gv);
                cst[m][q] = c;
                f16 hv = (f16)(sigm_(ov) * tanh_(c));
                int wt = ofs0 + q * 8;
                hb_w[(m * 8 + slot) * 512 + wt] = hv;
                hct[m * 8192 + wt] = hv;
            }
        }

        __syncthreads();   // single barrier per step; drains seq prefetch too
        cur ^= 1;
    }
}

// ---------------------------------------------------------------------------
// K3: out = h_cat(81920x512 f16, frag layout) @ W3p + out_b -> fp32 (B,10,512)
// 1280 blocks x 512 thr; block tile 64 rows x 512 cols; wave: 64x64.
// ---------------------------------------------------------------------------
__global__ __launch_bounds__(512) void out_gemm(
    const f16* __restrict__ hcat, const f16* __restrict__ W3p,
    const float* __restrict__ out_b, float* __restrict__ out) {
    const int mt0  = blockIdx.x << 2;
    const int wave = threadIdx.x >> 6;
    const int lane = threadIdx.x & 63;
    const int l16  = lane & 15;
    const int quad = lane >> 4;
    const int n0   = wave * 64;

    float bias_l[4];
#pragma unroll
    for (int nt = 0; nt < 4; ++nt) bias_l[nt] = out_b[n0 + nt * 16 + l16];

    f32x4 acc[4][4];
#pragma unroll
    for (int m = 0; m < 4; ++m)
#pragma unroll
        for (int nt = 0; nt < 4; ++nt)
#pragma unroll
            for (int q = 0; q < 4; ++q) acc[m][nt][q] = bias_l[nt];

#pragma unroll 2
    for (int kc = 0; kc < 16; ++kc) {
        f16x8 a[4], b[4];
#pragma unroll
        for (int m = 0; m < 4; ++m)
            a[m] = *(const f16x8*)(hcat + ((size_t)((mt0 + m) * 16 + kc) * 512 + lane * 8));
#pragma unroll
        for (int nt = 0; nt < 4; ++nt)
            b[nt] = *(const f16x8*)(W3p + ((kc * 32 + wave * 4 + nt) * 512 + lane * 8));
#pragma unroll
        for (int m = 0; m < 4; ++m)
#pragma unroll
            for (int nt = 0; nt < 4; ++nt)
                acc[m][nt] = __builtin_amdgcn_mfma_f32_16x16x32_f16(a[m], b[nt], acc[m][nt], 0, 0, 0);
    }

#pragma unroll
    for (int m = 0; m < 4; ++m) {
#pragma unroll
        for (int nt = 0; nt < 4; ++nt) {
#pragma unroll
            for (int q = 0; q < 4; ++q) {
                int R = mt0 * 16 + m * 16 + quad * 4 + q;
                int t = R >> 13;
                int b = R & 8191;
                out[(size_t)(b * 10 + t) * 512 + n0 + nt * 16 + l16] = acc[m][nt][q];
            }
        }
    }
}

// ---------------------------------------------------------------------------
extern "C" void kernel_launch(void* const* d_in, const int* in_sizes, int n_in,
                              void* d_out, int out_size, void* d_ws, size_t ws_size,
                              hipStream_t stream) {
    const int*   words   = (const int*)d_in[0];
    const int*   lengths = (const int*)d_in[1];
    const float* tab     = (const float*)d_in[2];
    const float* enc_w   = (const float*)d_in[3];
    const float* enc_b   = (const float*)d_in[4];
    const float* wih_f   = (const float*)d_in[5];
    const float* whh_f   = (const float*)d_in[6];
    const float* bih_f   = (const float*)d_in[7];
    const float* bhh_f   = (const float*)d_in[8];
    const float* wih_b   = (const float*)d_in[9];
    const float* whh_b   = (const float*)d_in[10];
    const float* bih_b   = (const float*)d_in[11];
    const float* bhh_b   = (const float*)d_in[12];
    const float* out_w   = (const float*)d_in[13];
    const float* out_b   = (const float*)d_in[14];
    float* out = (float*)d_out;

    char* ws = (char*)d_ws;
    f16*   Wp   = (f16*)(ws + 0);           //  2 MB
    f16*   W3p  = (f16*)(ws + 2097152);     //  0.5 MB
    float* bp   = (float*)(ws + 2621440);   //  8 KB
    float* P    = (float*)(ws + 2629632);   //  36 KB
    f16*   seqp = (f16*)(ws + 2666496);     //  40 MB
    f16*   hcat = (f16*)(ws + 44609536);    //  80 MB  (total ~122.6 MB)

    pack_w2<<<4096, 256, 0, stream>>>(wih_f, whh_f, wih_b, whh_b, Wp);
    pack_bias<<<8, 256, 0, stream>>>(bih_f, bhh_f, bih_b, bhh_b, bp);
    pack_w3<<<1024, 256, 0, stream>>>(out_w, W3p);
    enc_proj<<<36, 256, 0, stream>>>(tab, enc_w, enc_b, P);
    build_seq<<<10240, 256, 0, stream>>>(words, lengths, P, seqp);
    lstm_fused<<<256, 1024, 0, stream>>>(seqp, Wp, bp, hcat);
    out_gemm<<<1280, 512, 0, stream>>>(hcat, W3p, out_b, out);
}